// Round 9
// baseline (8132.552 us; speedup 1.0000x reference)
//
#include <hip/hip_runtime.h>
#include <stdint.h>

// PointerNet fused forward. B=512, S=50, E=H=128.
// 256 blocks x 1024 threads (16 waves), 2 batch elements per block.
// AMORTIZED M8 LAYOUT: wave w owns units 8w..8w+7; lane eighth e = l>>3 owns
// k-eighth k4 in [4e,4e+4); each thread loads each weight float4 ONCE and
// accumulates for BOTH batch elements (keeps L2 weight traffic halved).
// Reductions: shfl_xor 8+16+32 (q2: xor8 only). Gate finalization: eighths
// 0-3 -> be0, 4-7 -> be1 (writers e=0 / e=4); c persists per-thread.
// 16 waves/CU = 4 waves/SIMD -- the occupancy lever.
// ROUND-9 FIX: __launch_bounds__(1024) WITHOUT a min-waves arg. Round 8's
// (1024,4) clamped VGPRs to 64 -> massive scratch spill (FETCH 16.8 GB,
// VALUBusy 11%). A 1024-thread block already implies 4 waves/SIMD residency,
// giving a 128-VGPR cap -- enough for this kernel's ~100.
// RG/RP for both elements live in LDS (~111 KB, 1 block/CU).
// Softmax/sampling: wave 0 -> be0, wave 8 -> be1.
// Dot products accumulate in f64 (single rounding to f32); elementwise math
// replicates XLA CPU bit patterns (tanh rational poly, logistic-as-tanh,
// sequential softmax sum). Sampling replicates jax.random.categorical with
// THREEFRY PARTITIONABLE mode (JAX >= 0.5 default):
//   fold_in: key' = tf2x32(key, (0, t))
//   split (foldlike): k1 = tf2x32(key', (0, 0))   [both output words]
//   random_bits(32): bits[j] = o0 ^ o1 of tf2x32(k1, (0, j))
// uniform->gumbel exactly as jax._src.random; argmax with first-index ties.
// All cross-lane communication is LDS write -> __syncthreads -> read, or
// register shuffles (round-5 hardening; no unprotected LDS broadcasts).

#define OFF_PIH_E 0
#define OFF_PHH_E 65536
#define OFF_PIH_D 131072
#define OFF_PHH_D 196608
#define OFF_PQG   262144
#define OFF_PRG   278528
#define OFF_PQP   294912
#define OFF_PRP   311296
// ws total: 327680 floats = 1.31 MB

#define RSTR 132   // LDS row stride for RG/RP (16B-aligned)

#define TINYF 1.1754943508222875e-38f

static __device__ __forceinline__ float f_add(float a, float b){ return __fadd_rn(a,b); }
static __device__ __forceinline__ float f_mul(float a, float b){ return __fmul_rn(a,b); }
static __device__ __forceinline__ float f_sub(float a, float b){ return __fsub_rn(a,b); }

static __device__ __forceinline__ double shfl_xor_d(double v, int mask) {
  long long x = __double_as_longlong(v);
  int lo = (int)(x & 0xffffffffll);
  int hi = (int)(x >> 32);
  lo = __shfl_xor(lo, mask);
  hi = __shfl_xor(hi, mask);
  return __longlong_as_double(((long long)hi << 32) | (unsigned long long)(unsigned int)lo);
}
#define RED3(x) { x += shfl_xor_d(x, 8); x += shfl_xor_d(x, 16); x += shfl_xor_d(x, 32); }

// XLA CPU tanh: elemental_ir_emitter rational approximation, unfused mul/add.
static __device__ __forceinline__ float tanh_xla(float x) {
  float xc = fminf(fmaxf(x, -7.90531110763549805f), 7.90531110763549805f);
  float x2 = f_mul(xc, xc);
  float p;
  p = -2.76076847742355e-16f;
  p = f_add(f_mul(p, x2),  2.00018790482477e-13f);
  p = f_add(f_mul(p, x2), -8.60467152213735e-11f);
  p = f_add(f_mul(p, x2),  5.12229709037114e-08f);
  p = f_add(f_mul(p, x2),  1.48572235717979e-05f);
  p = f_add(f_mul(p, x2),  6.37261928875436e-04f);
  p = f_add(f_mul(p, x2),  4.89352455891786e-03f);
  p = f_mul(xc, p);
  float q;
  q = 1.19825839466702e-06f;
  q = f_add(f_mul(q, x2), 1.18534705686654e-04f);
  q = f_add(f_mul(q, x2), 2.26843463243900e-03f);
  q = f_add(f_mul(q, x2), 4.89352518554385e-03f);
  float r = __fdiv_rn(p, q);
  return (fabsf(x) < 0.0004f) ? x : r;
}

// XLA logistic expansion: 0.5 + 0.5*tanh(0.5*x)
static __device__ __forceinline__ float sigmoid_xla(float x) {
  return f_add(0.5f, f_mul(0.5f, tanh_xla(f_mul(0.5f, x))));
}

// Threefry-2x32, 20 rounds (JAX key schedule)
static __device__ __forceinline__ void tf2x32(uint32_t k0, uint32_t k1,
                                              uint32_t x0, uint32_t x1,
                                              uint32_t &o0, uint32_t &o1) {
  uint32_t ks2 = k0 ^ k1 ^ 0x1BD11BDAu;
  x0 += k0; x1 += k1;
#define TFR(r) { x0 += x1; x1 = (x1 << (r)) | (x1 >> (32 - (r))); x1 ^= x0; }
  TFR(13) TFR(15) TFR(26) TFR(6)
  x0 += k1;  x1 += ks2 + 1u;
  TFR(17) TFR(29) TFR(16) TFR(24)
  x0 += ks2; x1 += k0 + 2u;
  TFR(13) TFR(15) TFR(26) TFR(6)
  x0 += k0;  x1 += k1 + 3u;
  TFR(17) TFR(29) TFR(16) TFR(24)
  x0 += k1;  x1 += ks2 + 4u;
  TFR(13) TFR(15) TFR(26) TFR(6)
  x0 += ks2; x1 += k0 + 5u;
#undef TFR
  o0 = x0; o1 = x1;
}

// NOTE: parameter names must not collide with float4 member names (.x/.y/.z/.w)
#define ACC4(acc, Wv, Vv) \
  acc = fma((double)(Wv).x, (double)(Vv).x, acc); \
  acc = fma((double)(Wv).y, (double)(Vv).y, acc); \
  acc = fma((double)(Wv).z, (double)(Vv).z, acc); \
  acc = fma((double)(Wv).w, (double)(Vv).w, acc);

// Pack weights: LSTM [512,128] -> P[(k>>2)*2048 + r*4 + (k&3)]
//               attn [128,128] -> P[(k>>2)*512  + o*4 + (k&3)]
__global__ void prep_kernel(const float* __restrict__ eWih, const float* __restrict__ eWhh,
                            const float* __restrict__ dWih, const float* __restrict__ dWhh,
                            const float* __restrict__ gWq,  const float* __restrict__ gWref,
                            const float* __restrict__ pWq,  const float* __restrict__ pWref,
                            float* __restrict__ ws) {
  int id = blockIdx.x * blockDim.x + threadIdx.x;
  if (id < 262144) {
    int m = id >> 16, e = id & 65535;
    const float* src = (m == 0) ? eWih : (m == 1) ? eWhh : (m == 2) ? dWih : dWhh;
    int r = e >> 7, k = e & 127;
    ws[m * 65536 + (k >> 2) * 2048 + r * 4 + (k & 3)] = src[e];
  } else if (id < 327680) {
    int a = id - 262144;
    int m = a >> 14, e = a & 16383;
    const float* src = (m == 0) ? gWq : (m == 1) ? gWref : (m == 2) ? pWq : pWref;
    int o = e >> 7, k = e & 127;
    ws[262144 + m * 16384 + (k >> 2) * 512 + o * 4 + (k & 3)] = src[e];
  }
}

// Eighth-k LSTM step for BOTH batch elements; weights loaded once.
// Returns h_new for be = besel; c is this lane's cell state for its besel.
static __device__ __forceinline__ float lstm_step8(
    int u, int e, int besel,
    const float4* __restrict__ PIH, const float4* __restrict__ PHH,
    const float* __restrict__ bih, const float* __restrict__ bhh,
    const float4* __restrict__ xA, const float4* __restrict__ hA,
    const float4* __restrict__ xB, const float4* __restrict__ hB,
    float &c)
{
  double diA=0,dfA=0,dgA=0,ddA=0, eiA=0,efA=0,egA=0,eoA=0;
  double diB=0,dfB=0,dgB=0,ddB=0, eiB=0,efB=0,egB=0,eoB=0;
  const int kb = e * 4;
#pragma unroll
  for (int kk = 0; kk < 4; kk++) {
    int k4 = kb + ((kk + e) & 3);         // per-eighth rotation: bank-spread
    float4 w0 = PIH[k4 * 512 + u];
    float4 w1 = PIH[k4 * 512 + u + 128];
    float4 w2 = PIH[k4 * 512 + u + 256];
    float4 w3 = PIH[k4 * 512 + u + 384];
    float4 xvA = xA[k4]; float4 xvB = xB[k4];
    ACC4(diA, w0, xvA) ACC4(dfA, w1, xvA) ACC4(dgA, w2, xvA) ACC4(ddA, w3, xvA)
    ACC4(diB, w0, xvB) ACC4(dfB, w1, xvB) ACC4(dgB, w2, xvB) ACC4(ddB, w3, xvB)
    float4 v0 = PHH[k4 * 512 + u];
    float4 v1 = PHH[k4 * 512 + u + 128];
    float4 v2 = PHH[k4 * 512 + u + 256];
    float4 v3 = PHH[k4 * 512 + u + 384];
    float4 hvA = hA[k4]; float4 hvB = hB[k4];
    ACC4(eiA, v0, hvA) ACC4(efA, v1, hvA) ACC4(egA, v2, hvA) ACC4(eoA, v3, hvA)
    ACC4(eiB, v0, hvB) ACC4(efB, v1, hvB) ACC4(egB, v2, hvB) ACC4(eoB, v3, hvB)
  }
  RED3(diA) RED3(dfA) RED3(dgA) RED3(ddA)
  RED3(eiA) RED3(efA) RED3(egA) RED3(eoA)
  RED3(diB) RED3(dfB) RED3(dgB) RED3(ddB)
  RED3(eiB) RED3(efB) RED3(egB) RED3(eoB)
  double di = besel ? diB : diA, df = besel ? dfB : dfA;
  double dg = besel ? dgB : dgA, dd = besel ? ddB : ddA;
  double ei = besel ? eiB : eiA, ef = besel ? efB : efA;
  double eg = besel ? egB : egA, eo = besel ? eoB : eoA;
  // ((x@Wih^T + bih) + h@Whh^T) + bhh  -- XLA add tree order
  float gi = f_add(f_add(f_add((float)di, bih[u      ]), (float)ei), bhh[u      ]);
  float gf = f_add(f_add(f_add((float)df, bih[u + 128]), (float)ef), bhh[u + 128]);
  float gg = f_add(f_add(f_add((float)dg, bih[u + 256]), (float)eg), bhh[u + 256]);
  float go = f_add(f_add(f_add((float)dd, bih[u + 384]), (float)eo), bhh[u + 384]);
  float I = sigmoid_xla(gi);
  float F = sigmoid_xla(gf);
  float G = tanh_xla(gg);
  float O = sigmoid_xla(go);
  c = f_add(f_mul(F, c), f_mul(I, G));
  return f_mul(O, tanh_xla(c));
}

// Eighth-k 128x128 matvec for BOTH batch elements (weights loaded once).
static __device__ __forceinline__ float mv_step8(
    int u, int e, int besel,
    const float4* __restrict__ PW, const float* __restrict__ bias,
    const float4* __restrict__ xA, const float4* __restrict__ xB)
{
  double aA = 0, aB = 0;
  const int kb = e * 4;
#pragma unroll
  for (int kk = 0; kk < 4; kk++) {
    int k4 = kb + ((kk + e) & 3);
    float4 wv = PW[k4 * 128 + u];
    float4 xvA = xA[k4]; float4 xvB = xB[k4];
    ACC4(aA, wv, xvA) ACC4(aB, wv, xvB)
  }
  RED3(aA) RED3(aB)
  double tot = besel ? aB : aA;
  return f_add((float)tot, bias[u]);
}

__global__ void __launch_bounds__(1024)
pnet_kernel(const float* __restrict__ bi, const float* __restrict__ emb,
            const float* __restrict__ ebih, const float* __restrict__ ebhh,
            const float* __restrict__ dbih, const float* __restrict__ dbhh,
            const float* __restrict__ gbq, const float* __restrict__ gbref, const float* __restrict__ gV,
            const float* __restrict__ pbq, const float* __restrict__ pbref, const float* __restrict__ pV,
            const float* __restrict__ dstart,
            float* __restrict__ ws, float* __restrict__ out)
{
  __shared__ __align__(16) float sRG[2][50 * RSTR];   // 52.8 KB
  __shared__ __align__(16) float sRP[2][50 * RSTR];   // 52.8 KB
  __shared__ __align__(16) float sh_x[2][128];
  __shared__ __align__(16) float sh_h[2][128];
  __shared__ __align__(16) float sh_q[2][128];
  __shared__ __align__(16) float sh_q2[2][128];
  __shared__ float sh_att[2][64];
  __shared__ float sh_w[2][64];
  __shared__ unsigned long long sh_msk[2];
  __shared__ int sh_idx[2];

  const int tid   = threadIdx.x;            // 0..1023
  const int l     = tid & 63;               // lane
  const int w     = tid >> 6;               // wave 0..15
  const int u     = w * 8 + (l & 7);        // unit 0..127
  const int e     = l >> 3;                 // k-eighth 0..7
  const int besel = e >> 2;                 // which be this lane finalizes
  const bool wr   = (e & 3) == 0;           // writer lanes (e=0 -> be0, e=4 -> be1)
  const int gb2   = blockIdx.x * 2;         // first batch element of block

  const float4* PIH_E = (const float4*)(ws + OFF_PIH_E);
  const float4* PHH_E = (const float4*)(ws + OFF_PHH_E);
  const float4* PIH_D = (const float4*)(ws + OFF_PIH_D);
  const float4* PHH_D = (const float4*)(ws + OFF_PHH_D);
  const float4* PQG = (const float4*)(ws + OFF_PQG);
  const float4* PRG = (const float4*)(ws + OFF_PRG);
  const float4* PQP = (const float4*)(ws + OFF_PQP);
  const float4* PRP = (const float4*)(ws + OFF_PRP);

  const float NEG_INF = -__builtin_inff();

  if (tid < 128) { sh_h[0][tid] = 0.0f; sh_h[1][tid] = 0.0f; }
  if (tid == 0) { sh_msk[0] = 0ull; sh_msk[1] = 0ull; }
  float c_st = 0.0f;
  __syncthreads();

  // ---------------- encoder + fused ref projections ----------------
  for (int t = 0; t < 50; t++) {
    if (wr) {
      float x0 = bi[(gb2 + besel) * 100 + t];
      float x1 = bi[(gb2 + besel) * 100 + 50 + t];
      sh_x[besel][u] = __fmaf_rn(x1, emb[128 + u], f_mul(x0, emb[u]));
    }
    __syncthreads();
    float hn = lstm_step8(u, e, besel, PIH_E, PHH_E, ebih, ebhh,
                          (const float4*)sh_x[0], (const float4*)sh_h[0],
                          (const float4*)sh_x[1], (const float4*)sh_h[1], c_st);
    __syncthreads();
    if (wr) sh_h[besel][u] = hn;
    __syncthreads();
    // rg/rp[t][u] (Conv1d k=1 fused), both be, weights loaded once
    {
      double agA = 0, apA = 0, agB = 0, apB = 0;
      const int kb = e * 4;
      const float4* hA4 = (const float4*)sh_h[0];
      const float4* hB4 = (const float4*)sh_h[1];
#pragma unroll
      for (int kk = 0; kk < 4; kk++) {
        int k4 = kb + ((kk + e) & 3);
        float4 wg = PRG[k4 * 128 + u];
        float4 wp = PRP[k4 * 128 + u];
        float4 xvA = hA4[k4]; float4 xvB = hB4[k4];
        ACC4(agA, wg, xvA) ACC4(agB, wg, xvB)
        ACC4(apA, wp, xvA) ACC4(apB, wp, xvB)
      }
      RED3(agA) RED3(agB) RED3(apA) RED3(apB)
      if (wr) {
        sRG[besel][t * RSTR + u] = f_add((float)(besel ? agB : agA), gbref[u]);
        sRP[besel][t * RSTR + u] = f_add((float)(besel ? apB : apA), pbref[u]);
      }
    }
    // loop-top sh_x write guarded by the barrier right after it
  }
  if (wr) sh_x[besel][u] = dstart[u];   // decoder initial input
  __syncthreads();

  // ---------------- decoder ----------------
  for (int t = 0; t < 50; t++) {
    // partitionable threefry:
    //   fk = fold_in(key(42), t) = tf((0,42), (0,t))
    //   k1 = split(fk, 2)[0]     = tf(fk, (0,0))   [foldlike: both words]
    uint32_t f0, f1, k1a, k1b;
    tf2x32(0u, 42u, 0u, (uint32_t)t, f0, f1);
    tf2x32(f0, f1, 0u, 0u, k1a, k1b);

    float hn = lstm_step8(u, e, besel, PIH_D, PHH_D, dbih, dbhh,
                          (const float4*)sh_x[0], (const float4*)sh_h[0],
                          (const float4*)sh_x[1], (const float4*)sh_h[1], c_st);
    __syncthreads();                                  // B1
    if (wr) sh_h[besel][u] = hn;
    __syncthreads();                                  // B2

    // glimpse query: qg = Wq_g @ h + bq_g (both be)
    {
      float qv = mv_step8(u, e, besel, PQG, gbq,
                          (const float4*)sh_h[0], (const float4*)sh_h[1]);
      if (wr) sh_q[besel][u] = qv;
    }
    __syncthreads();                                  // B3

    // glimpse logits: lg[s] = sum_h V[h]*tanh(qg[h]+ref_g[s][h]); 8 lanes/row
    {
      double acc = 0.0;
      const int r = tid & 511;
      const int be = tid >> 9;
      const int s = r >> 3;
      const int f4o = (r & 7) * 4;        // float4 offset within the 32
      if (r < 400) {
        const float4* rr = (const float4*)(&sRG[be][s * RSTR]) + f4o;
        const float4* qq = (const float4*)(sh_q[be]) + f4o;
        const float4* vvp = (const float4*)gV + f4o;
#pragma unroll
        for (int k4 = 0; k4 < 4; k4++) {
          float4 rv = rr[k4];
          float4 qv = qq[k4];
          float4 gvv = vvp[k4];
          acc = fma((double)gvv.x, (double)tanh_xla(f_add(qv.x, rv.x)), acc);
          acc = fma((double)gvv.y, (double)tanh_xla(f_add(qv.y, rv.y)), acc);
          acc = fma((double)gvv.z, (double)tanh_xla(f_add(qv.z, rv.z)), acc);
          acc = fma((double)gvv.w, (double)tanh_xla(f_add(qv.w, rv.w)), acc);
        }
      }
      double tot = acc + shfl_xor_d(acc, 1);
      tot = tot + shfl_xor_d(tot, 2);
      tot = tot + shfl_xor_d(tot, 4);
      if (r < 400 && (r & 7) == 0) {
        float lg = (float)tot;
        sh_att[be][s] = ((sh_msk[be] >> s) & 1ull) ? NEG_INF : lg;
      }
      if (r >= 400 && r < 414) sh_att[be][r - 350] = NEG_INF;   // pad 50..63
    }
    __syncthreads();                                  // B4

    // glimpse softmax: wave 0 -> be0, wave 8 -> be1
    if ((w & 7) == 0) {
      const int be = w >> 3;
      float v = sh_att[be][l];
      float m = v;
      for (int off = 32; off > 0; off >>= 1) m = fmaxf(m, __shfl_xor(m, off));
      float ex = (l < 50) ? expf(f_sub(v, m)) : 0.0f;
      float ss = 0.0f;
      for (int s2 = 0; s2 < 50; s2++) ss = f_add(ss, __shfl(ex, s2));
      float wv = __fdiv_rn(ex, ss);
      sh_w[be][l] = (l < 50) ? wv : 0.0f;
    }
    __syncthreads();                                  // B5

    // q2 = sum_s w[s]*ref_g[s][:]; s-halves by (e&1), combine xor8; both be
    {
      double aA = 0, aB = 0;
      const int s0 = (e & 1) * 25;
      for (int s2 = s0; s2 < s0 + 25; s2++) {
        float wvA = sh_w[0][s2];
        float wvB = sh_w[1][s2];
        aA = fma((double)sRG[0][s2 * RSTR + u], (double)wvA, aA);
        aB = fma((double)sRG[1][s2 * RSTR + u], (double)wvB, aB);
      }
      aA += shfl_xor_d(aA, 8);
      aB += shfl_xor_d(aB, 8);
      if (wr) sh_q2[besel][u] = (float)(besel ? aB : aA);
    }
    __syncthreads();                                  // B6

    // pointer query: qp = Wq_p @ q2 + bq_p (both be)
    {
      float qv = mv_step8(u, e, besel, PQP, pbq,
                          (const float4*)sh_q2[0], (const float4*)sh_q2[1]);
      if (wr) sh_q[besel][u] = qv;
    }
    __syncthreads();                                  // B7

    // pointer logits + 10*tanh + mask; 8 lanes/row
    {
      double acc = 0.0;
      const int r = tid & 511;
      const int be = tid >> 9;
      const int s = r >> 3;
      const int f4o = (r & 7) * 4;
      if (r < 400) {
        const float4* rr = (const float4*)(&sRP[be][s * RSTR]) + f4o;
        const float4* qq = (const float4*)(sh_q[be]) + f4o;
        const float4* vvp = (const float4*)pV + f4o;
#pragma unroll
        for (int k4 = 0; k4 < 4; k4++) {
          float4 rv = rr[k4];
          float4 qv = qq[k4];
          float4 pvv = vvp[k4];
          acc = fma((double)pvv.x, (double)tanh_xla(f_add(qv.x, rv.x)), acc);
          acc = fma((double)pvv.y, (double)tanh_xla(f_add(qv.y, rv.y)), acc);
          acc = fma((double)pvv.z, (double)tanh_xla(f_add(qv.z, rv.z)), acc);
          acc = fma((double)pvv.w, (double)tanh_xla(f_add(qv.w, rv.w)), acc);
        }
      }
      double tot = acc + shfl_xor_d(acc, 1);
      tot = tot + shfl_xor_d(tot, 2);
      tot = tot + shfl_xor_d(tot, 4);
      if (r < 400 && (r & 7) == 0) {
        float lp = (float)tot;
        lp = f_mul(10.0f, tanh_xla(lp));
        sh_att[be][s] = ((sh_msk[be] >> s) & 1ull) ? NEG_INF : lp;
      }
      if (r >= 400 && r < 414) sh_att[be][r - 350] = NEG_INF;
    }
    __syncthreads();                                  // B8

    // probs output + gumbel sampling: wave 0 -> be0, wave 8 -> be1
    if ((w & 7) == 0) {
      const int be = w >> 3;
      float v = sh_att[be][l];
      float m = v;
      for (int off = 32; off > 0; off >>= 1) m = fmaxf(m, __shfl_xor(m, off));
      float ex = (l < 50) ? expf(f_sub(v, m)) : 0.0f;
      float ss = 0.0f;
      for (int s2 = 0; s2 < 50; s2++) ss = f_add(ss, __shfl(ex, s2));
      if (l < 50) out[t * 25600 + (gb2 + be) * 50 + l] = __fdiv_rn(ex, ss);

      float val = NEG_INF;
      int ii = l;
      if (l < 50) {
        int j = (gb2 + be) * 50 + l;       // flat index into (B,S) gumbel draw
        // partitionable random_bits(32): bits[j] = o0 ^ o1 of tf(k1, (0, j))
        uint32_t b0, b1;
        tf2x32(k1a, k1b, 0u, (uint32_t)j, b0, b1);
        uint32_t bits = b0 ^ b1;
        float fl = __uint_as_float((bits >> 9) | 0x3f800000u) - 1.0f;  // [0,1)
        float uu = f_add(fl, TINYF);
        uu = fmaxf(TINYF, uu);
        float gum = -logf(-logf(uu));
        val = f_add(v, gum);               // -inf stays -inf for masked
      }
      // argmax, first-index tiebreak (jnp.argmax semantics)
      for (int off = 32; off > 0; off >>= 1) {
        float ov = __shfl_down(val, off);
        int   oi = __shfl_down(ii, off);
        if (ov > val || (ov == val && oi < ii)) { val = ov; ii = oi; }
      }
      if (l == 0) {
        sh_idx[be] = ii;
        sh_msk[be] |= (1ull << ii);        // masks step t+1 onward
        out[1280000 + t * 512 + gb2 + be] = (float)ii;
      }
    }
    __syncthreads();                                  // B9

    // next decoder input: embedded[b, idx]
    if (wr) {
      int idx = sh_idx[besel];
      float x0 = bi[(gb2 + besel) * 100 + idx];
      float x1 = bi[(gb2 + besel) * 100 + 50 + idx];
      sh_x[besel][u] = __fmaf_rn(x1, emb[128 + u], f_mul(x0, emb[u]));
    }
    __syncthreads();                                  // B10
  }
}

extern "C" void kernel_launch(void* const* d_in, const int* in_sizes, int n_in,
                              void* d_out, int out_size, void* d_ws, size_t ws_size,
                              hipStream_t stream) {
  const float* bi     = (const float*)d_in[0];
  const float* emb    = (const float*)d_in[1];
  const float* eWih   = (const float*)d_in[2];
  const float* eWhh   = (const float*)d_in[3];
  const float* ebih   = (const float*)d_in[4];
  const float* ebhh   = (const float*)d_in[5];
  const float* dWih   = (const float*)d_in[6];
  const float* dWhh   = (const float*)d_in[7];
  const float* dbih   = (const float*)d_in[8];
  const float* dbhh   = (const float*)d_in[9];
  const float* gWq    = (const float*)d_in[10];
  const float* gbq    = (const float*)d_in[11];
  const float* gWref  = (const float*)d_in[12];
  const float* gbref  = (const float*)d_in[13];
  const float* gV     = (const float*)d_in[14];
  const float* pWq    = (const float*)d_in[15];
  const float* pbq    = (const float*)d_in[16];
  const float* pWref  = (const float*)d_in[17];
  const float* pbref  = (const float*)d_in[18];
  const float* pV     = (const float*)d_in[19];
  const float* dstart = (const float*)d_in[20];
  float* ws  = (float*)d_ws;
  float* out = (float*)d_out;

  hipLaunchKernelGGL(prep_kernel, dim3(1280), dim3(256), 0, stream,
                     eWih, eWhh, dWih, dWhh, gWq, gWref, pWq, pWref, ws);
  hipLaunchKernelGGL(pnet_kernel, dim3(256), dim3(1024), 0, stream,
                     bi, emb, ebih, ebhh, dbih, dbhh,
                     gbq, gbref, gV, pbq, pbref, pV, dstart, ws, out);
}

// Round 10
// 1725.282 us; speedup vs baseline: 4.7138x; 4.7138x over previous
//
#include <hip/hip_runtime.h>
#include <stdint.h>

// PointerNet fused forward. B=512, S=50, E=H=128.
// 256 blocks x 1024 threads (16 waves), 2 batch elements per block.
// WAVE-SPECIALIZED LSTM (round 10): the 1024-thread compiler VGPR cap is 64
// (observed R8/R9), so the LSTM is decomposed so no phase needs more:
//   wave w = (g = w&3, uh = (w>>2)&1, kh = w>>3):
//     lane computes ONE full 128-k f64 dot (gate g, unit uh*64+l) of
//     x.Wih (kh=0) or h.Whh (kh=1), for BOTH batch elements (weights loaded
//     once per block -> L2 traffic stays halved), writes f64 dots to LDS
//     gacc[kh][be][g][u]. After barrier, threads 0..255 (be=tid>>7,u=tid&127)
//     do the gate/cell pointwise math; c persists in their registers.
// Numerics identical to passing rounds 5-9: full-f64 x-dot/h-dot, gate sum
// f_add(f_add(f_add((float)di,bih),(float)ei),bhh), XLA tanh poly,
// logistic-as-tanh, sequential softmax sum, f64 attention dots.
// Sampling: jax.random.categorical, THREEFRY PARTITIONABLE mode:
//   fold_in: key' = tf2x32(key, (0, t))
//   split (foldlike): k1 = tf2x32(key', (0, 0))   [both output words]
//   random_bits(32): bits[j] = o0 ^ o1 of tf2x32(k1, (0, j))
// gumbel exactly as jax._src.random; argmax with first-index ties.
// RG/RP in LDS (~106 KB) + gacc (16 KB) -> ~127 KB, 1 block/CU, 16 waves/CU.
// All cross-lane communication: LDS write -> __syncthreads -> read, or
// register shuffles (round-5 hardening).

#define OFF_PIH_E 0
#define OFF_PHH_E 65536
#define OFF_PIH_D 131072
#define OFF_PHH_D 196608
#define OFF_PQG   262144
#define OFF_PRG   278528
#define OFF_PQP   294912
#define OFF_PRP   311296
// ws total: 327680 floats = 1.31 MB

#define RSTR 132   // LDS row stride for RG/RP (16B-aligned)

#define TINYF 1.1754943508222875e-38f

static __device__ __forceinline__ float f_add(float a, float b){ return __fadd_rn(a,b); }
static __device__ __forceinline__ float f_mul(float a, float b){ return __fmul_rn(a,b); }
static __device__ __forceinline__ float f_sub(float a, float b){ return __fsub_rn(a,b); }

static __device__ __forceinline__ double shfl_xor_d(double v, int mask) {
  long long x = __double_as_longlong(v);
  int lo = (int)(x & 0xffffffffll);
  int hi = (int)(x >> 32);
  lo = __shfl_xor(lo, mask);
  hi = __shfl_xor(hi, mask);
  return __longlong_as_double(((long long)hi << 32) | (unsigned long long)(unsigned int)lo);
}

// XLA CPU tanh: elemental_ir_emitter rational approximation, unfused mul/add.
static __device__ __forceinline__ float tanh_xla(float x) {
  float xc = fminf(fmaxf(x, -7.90531110763549805f), 7.90531110763549805f);
  float x2 = f_mul(xc, xc);
  float p;
  p = -2.76076847742355e-16f;
  p = f_add(f_mul(p, x2),  2.00018790482477e-13f);
  p = f_add(f_mul(p, x2), -8.60467152213735e-11f);
  p = f_add(f_mul(p, x2),  5.12229709037114e-08f);
  p = f_add(f_mul(p, x2),  1.48572235717979e-05f);
  p = f_add(f_mul(p, x2),  6.37261928875436e-04f);
  p = f_add(f_mul(p, x2),  4.89352455891786e-03f);
  p = f_mul(xc, p);
  float q;
  q = 1.19825839466702e-06f;
  q = f_add(f_mul(q, x2), 1.18534705686654e-04f);
  q = f_add(f_mul(q, x2), 2.26843463243900e-03f);
  q = f_add(f_mul(q, x2), 4.89352518554385e-03f);
  float r = __fdiv_rn(p, q);
  return (fabsf(x) < 0.0004f) ? x : r;
}

// XLA logistic expansion: 0.5 + 0.5*tanh(0.5*x)
static __device__ __forceinline__ float sigmoid_xla(float x) {
  return f_add(0.5f, f_mul(0.5f, tanh_xla(f_mul(0.5f, x))));
}

// Threefry-2x32, 20 rounds (JAX key schedule)
static __device__ __forceinline__ void tf2x32(uint32_t k0, uint32_t k1,
                                              uint32_t x0, uint32_t x1,
                                              uint32_t &o0, uint32_t &o1) {
  uint32_t ks2 = k0 ^ k1 ^ 0x1BD11BDAu;
  x0 += k0; x1 += k1;
#define TFR(r) { x0 += x1; x1 = (x1 << (r)) | (x1 >> (32 - (r))); x1 ^= x0; }
  TFR(13) TFR(15) TFR(26) TFR(6)
  x0 += k1;  x1 += ks2 + 1u;
  TFR(17) TFR(29) TFR(16) TFR(24)
  x0 += ks2; x1 += k0 + 2u;
  TFR(13) TFR(15) TFR(26) TFR(6)
  x0 += k0;  x1 += k1 + 3u;
  TFR(17) TFR(29) TFR(16) TFR(24)
  x0 += k1;  x1 += ks2 + 4u;
  TFR(13) TFR(15) TFR(26) TFR(6)
  x0 += ks2; x1 += k0 + 5u;
#undef TFR
  o0 = x0; o1 = x1;
}

// NOTE: parameter names must not collide with float4 member names (.x/.y/.z/.w)
#define ACC4(acc, Wv, Vv) \
  acc = fma((double)(Wv).x, (double)(Vv).x, acc); \
  acc = fma((double)(Wv).y, (double)(Vv).y, acc); \
  acc = fma((double)(Wv).z, (double)(Vv).z, acc); \
  acc = fma((double)(Wv).w, (double)(Vv).w, acc);

// Pack weights: LSTM [512,128] -> P[(k>>2)*2048 + r*4 + (k&3)]
//               attn [128,128] -> P[(k>>2)*512  + o*4 + (k&3)]
__global__ void prep_kernel(const float* __restrict__ eWih, const float* __restrict__ eWhh,
                            const float* __restrict__ dWih, const float* __restrict__ dWhh,
                            const float* __restrict__ gWq,  const float* __restrict__ gWref,
                            const float* __restrict__ pWq,  const float* __restrict__ pWref,
                            float* __restrict__ ws) {
  int id = blockIdx.x * blockDim.x + threadIdx.x;
  if (id < 262144) {
    int m = id >> 16, e = id & 65535;
    const float* src = (m == 0) ? eWih : (m == 1) ? eWhh : (m == 2) ? dWih : dWhh;
    int r = e >> 7, k = e & 127;
    ws[m * 65536 + (k >> 2) * 2048 + r * 4 + (k & 3)] = src[e];
  } else if (id < 327680) {
    int a = id - 262144;
    int m = a >> 14, e = a & 16383;
    const float* src = (m == 0) ? gWq : (m == 1) ? gWref : (m == 2) ? pWq : pWref;
    int o = e >> 7, k = e & 127;
    ws[262144 + m * 16384 + (k >> 2) * 512 + o * 4 + (k & 3)] = src[e];
  }
}

// One full 128-k f64 dot of P-row `grow` against two LDS vectors (be0, be1).
// P stride 512 float4 per k4 (LSTM pack). 2 partials per be for ILP.
static __device__ __forceinline__ void dot512(
    const float4* __restrict__ P, int grow,
    const float4* __restrict__ sA, const float4* __restrict__ sB,
    double &outA, double &outB)
{
  double a0 = 0, a1 = 0, b0 = 0, b1 = 0;
#pragma unroll 4
  for (int k4 = 0; k4 < 32; k4 += 2) {
    float4 w0 = P[k4 * 512 + grow];
    float4 w1 = P[(k4 + 1) * 512 + grow];
    float4 xa0 = sA[k4]; float4 xa1 = sA[k4 + 1];
    float4 xb0 = sB[k4]; float4 xb1 = sB[k4 + 1];
    ACC4(a0, w0, xa0) ACC4(a1, w1, xa1)
    ACC4(b0, w0, xb0) ACC4(b1, w1, xb1)
  }
  outA = a0 + a1;
  outB = b0 + b1;
}

// Same, for 128x128 attn pack (stride 128 float4 per k4), one be vector.
static __device__ __forceinline__ double dot128(
    const float4* __restrict__ P, int row, const float4* __restrict__ src)
{
  double a0 = 0, a1 = 0;
#pragma unroll 4
  for (int k4 = 0; k4 < 32; k4 += 2) {
    float4 w0 = P[k4 * 128 + row];
    float4 w1 = P[(k4 + 1) * 128 + row];
    float4 x0 = src[k4]; float4 x1 = src[k4 + 1];
    ACC4(a0, w0, x0) ACC4(a1, w1, x1)
  }
  return a0 + a1;
}

__global__ void __launch_bounds__(1024)
pnet_kernel(const float* __restrict__ bi, const float* __restrict__ emb,
            const float* __restrict__ ebih, const float* __restrict__ ebhh,
            const float* __restrict__ dbih, const float* __restrict__ dbhh,
            const float* __restrict__ gbq, const float* __restrict__ gbref, const float* __restrict__ gV,
            const float* __restrict__ pbq, const float* __restrict__ pbref, const float* __restrict__ pV,
            const float* __restrict__ dstart,
            float* __restrict__ ws, float* __restrict__ out)
{
  __shared__ __align__(16) float sRG[2][50 * RSTR];   // 52.8 KB
  __shared__ __align__(16) float sRP[2][50 * RSTR];   // 52.8 KB
  __shared__ __align__(16) double gacc[2][2][4][128]; // 16 KB: [kh][be][g][u]
  __shared__ __align__(16) float sh_x[2][128];
  __shared__ __align__(16) float sh_h[2][128];
  __shared__ __align__(16) float sh_q[2][128];
  __shared__ __align__(16) float sh_q2[2][128];
  __shared__ float sh_att[2][64];
  __shared__ float sh_w[2][64];
  __shared__ unsigned long long sh_msk[2];
  __shared__ int sh_idx[2];

  const int tid = threadIdx.x;              // 0..1023
  const int l   = tid & 63;                 // lane
  const int w   = tid >> 6;                 // wave 0..15
  // LSTM wave roles:
  const int g     = w & 3;                  // gate i/f/g/o
  const int uh    = (w >> 2) & 1;           // unit half
  const int kh    = w >> 3;                 // 0: x.Wih, 1: h.Whh
  const int ulane = uh * 64 + l;            // unit 0..127
  const int grow  = g * 128 + ulane;        // weight row
  // pointwise-role (tid<256):
  const int cu_be = tid >> 7;
  const int cu_u  = tid & 127;
  const int gb2   = blockIdx.x * 2;

  const float4* PIH_E = (const float4*)(ws + OFF_PIH_E);
  const float4* PHH_E = (const float4*)(ws + OFF_PHH_E);
  const float4* PIH_D = (const float4*)(ws + OFF_PIH_D);
  const float4* PHH_D = (const float4*)(ws + OFF_PHH_D);
  const float4* PQG = (const float4*)(ws + OFF_PQG);
  const float4* PRG = (const float4*)(ws + OFF_PRG);
  const float4* PQP = (const float4*)(ws + OFF_PQP);
  const float4* PRP = (const float4*)(ws + OFF_PRP);

  const float NEG_INF = -__builtin_inff();

  if (tid < 256) sh_h[cu_be][cu_u] = 0.0f;
  if (tid == 0) { sh_msk[0] = 0ull; sh_msk[1] = 0ull; }
  float c_st = 0.0f;                        // cell state (tid<256 only)
  __syncthreads();

  // ---------------- encoder + fused ref projections ----------------
  for (int t = 0; t < 50; t++) {
    if (tid < 256) {
      float x0 = bi[(gb2 + cu_be) * 100 + t];
      float x1 = bi[(gb2 + cu_be) * 100 + 50 + t];
      sh_x[cu_be][cu_u] = __fmaf_rn(x1, emb[128 + cu_u], f_mul(x0, emb[cu_u]));
    }
    __syncthreads();                               // E1: x ready
    {
      const float4* P  = kh ? PHH_E : PIH_E;
      const float4* sA = kh ? (const float4*)sh_h[0] : (const float4*)sh_x[0];
      const float4* sB = kh ? (const float4*)sh_h[1] : (const float4*)sh_x[1];
      double dA, dB;
      dot512(P, grow, sA, sB, dA, dB);
      gacc[kh][0][g][ulane] = dA;
      gacc[kh][1][g][ulane] = dB;
    }
    __syncthreads();                               // E2: gacc ready, sh_h free
    if (tid < 256) {
      float gi = f_add(f_add(f_add((float)gacc[0][cu_be][0][cu_u], ebih[cu_u      ]), (float)gacc[1][cu_be][0][cu_u]), ebhh[cu_u      ]);
      float gf = f_add(f_add(f_add((float)gacc[0][cu_be][1][cu_u], ebih[cu_u + 128]), (float)gacc[1][cu_be][1][cu_u]), ebhh[cu_u + 128]);
      float gg = f_add(f_add(f_add((float)gacc[0][cu_be][2][cu_u], ebih[cu_u + 256]), (float)gacc[1][cu_be][2][cu_u]), ebhh[cu_u + 256]);
      float go = f_add(f_add(f_add((float)gacc[0][cu_be][3][cu_u], ebih[cu_u + 384]), (float)gacc[1][cu_be][3][cu_u]), ebhh[cu_u + 384]);
      float I = sigmoid_xla(gi);
      float F = sigmoid_xla(gf);
      float G = tanh_xla(gg);
      float O = sigmoid_xla(go);
      c_st = f_add(f_mul(F, c_st), f_mul(I, G));
      sh_h[cu_be][cu_u] = f_mul(O, tanh_xla(c_st));
    }
    __syncthreads();                               // E3: h ready
    // ref projections: 8 waves, one full 128-dot per lane
    if (w < 8) {
      int dot = (w << 6) | l;                      // 0..511
      int sel = dot >> 8, be = (dot >> 7) & 1, u2 = dot & 127;
      const float4* PR = sel ? PRP : PRG;
      const float* bias = sel ? pbref : gbref;
      double a = dot128(PR, u2, (const float4*)sh_h[be]);
      float val = f_add((float)a, bias[u2]);
      if (sel) sRP[be][t * RSTR + u2] = val;
      else     sRG[be][t * RSTR + u2] = val;
    }
    // loop-top sh_x write: LSTM readers finished at E2; refproj ignores sh_x.
  }
  if (tid < 256) sh_x[cu_be][cu_u] = dstart[cu_u];  // decoder initial input
  __syncthreads();

  // ---------------- decoder ----------------
  for (int t = 0; t < 50; t++) {
    // partitionable threefry:
    //   fk = fold_in(key(42), t) = tf((0,42), (0,t))
    //   k1 = split(fk, 2)[0]     = tf(fk, (0,0))   [foldlike: both words]
    uint32_t f0, f1, k1a, k1b;
    tf2x32(0u, 42u, 0u, (uint32_t)t, f0, f1);
    tf2x32(f0, f1, 0u, 0u, k1a, k1b);

    {
      const float4* P  = kh ? PHH_D : PIH_D;
      const float4* sA = kh ? (const float4*)sh_h[0] : (const float4*)sh_x[0];
      const float4* sB = kh ? (const float4*)sh_h[1] : (const float4*)sh_x[1];
      double dA, dB;
      dot512(P, grow, sA, sB, dA, dB);
      gacc[kh][0][g][ulane] = dA;
      gacc[kh][1][g][ulane] = dB;
    }
    __syncthreads();                               // B1
    if (tid < 256) {
      float gi = f_add(f_add(f_add((float)gacc[0][cu_be][0][cu_u], dbih[cu_u      ]), (float)gacc[1][cu_be][0][cu_u]), dbhh[cu_u      ]);
      float gf = f_add(f_add(f_add((float)gacc[0][cu_be][1][cu_u], dbih[cu_u + 128]), (float)gacc[1][cu_be][1][cu_u]), dbhh[cu_u + 128]);
      float gg = f_add(f_add(f_add((float)gacc[0][cu_be][2][cu_u], dbih[cu_u + 256]), (float)gacc[1][cu_be][2][cu_u]), dbhh[cu_u + 256]);
      float go = f_add(f_add(f_add((float)gacc[0][cu_be][3][cu_u], dbih[cu_u + 384]), (float)gacc[1][cu_be][3][cu_u]), dbhh[cu_u + 384]);
      float I = sigmoid_xla(gi);
      float F = sigmoid_xla(gf);
      float G = tanh_xla(gg);
      float O = sigmoid_xla(go);
      c_st = f_add(f_mul(F, c_st), f_mul(I, G));
      sh_h[cu_be][cu_u] = f_mul(O, tanh_xla(c_st));
    }
    __syncthreads();                               // B2: h ready

    // glimpse query: qg = Wq_g @ h + bq_g (4 waves)
    if (w < 4) {
      int dot = (w << 6) | l;                      // 0..255
      int be = dot >> 7, u2 = dot & 127;
      double a = dot128(PQG, u2, (const float4*)sh_h[be]);
      sh_q[be][u2] = f_add((float)a, gbq[u2]);
    }
    __syncthreads();                               // B3

    // glimpse logits: 8 lanes/row
    {
      double acc = 0.0;
      const int r = tid & 511;
      const int be = tid >> 9;
      const int s = r >> 3;
      const int f4o = (r & 7) * 4;
      if (r < 400) {
        const float4* rr = (const float4*)(&sRG[be][s * RSTR]) + f4o;
        const float4* qq = (const float4*)(sh_q[be]) + f4o;
        const float4* vvp = (const float4*)gV + f4o;
#pragma unroll
        for (int k4 = 0; k4 < 4; k4++) {
          float4 rv = rr[k4];
          float4 qv = qq[k4];
          float4 gvv = vvp[k4];
          acc = fma((double)gvv.x, (double)tanh_xla(f_add(qv.x, rv.x)), acc);
          acc = fma((double)gvv.y, (double)tanh_xla(f_add(qv.y, rv.y)), acc);
          acc = fma((double)gvv.z, (double)tanh_xla(f_add(qv.z, rv.z)), acc);
          acc = fma((double)gvv.w, (double)tanh_xla(f_add(qv.w, rv.w)), acc);
        }
      }
      double tot = acc + shfl_xor_d(acc, 1);
      tot = tot + shfl_xor_d(tot, 2);
      tot = tot + shfl_xor_d(tot, 4);
      if (r < 400 && (r & 7) == 0) {
        float lg = (float)tot;
        sh_att[be][s] = ((sh_msk[be] >> s) & 1ull) ? NEG_INF : lg;
      }
      if (r >= 400 && r < 414) sh_att[be][r - 350] = NEG_INF;   // pad 50..63
    }
    __syncthreads();                               // B4

    // glimpse softmax: wave 0 -> be0, wave 8 -> be1
    if ((w & 7) == 0) {
      const int be = w >> 3;
      float v = sh_att[be][l];
      float m = v;
      for (int off = 32; off > 0; off >>= 1) m = fmaxf(m, __shfl_xor(m, off));
      float ex = (l < 50) ? expf(f_sub(v, m)) : 0.0f;
      float ss = 0.0f;
      for (int s2 = 0; s2 < 50; s2++) ss = f_add(ss, __shfl(ex, s2));
      float wv = __fdiv_rn(ex, ss);
      sh_w[be][l] = (l < 50) ? wv : 0.0f;
    }
    __syncthreads();                               // B5

    // q2 = sum_s w[s]*ref_g[s][:] (4 waves, sequential s -- XLA order)
    if (w < 4) {
      int dot = (w << 6) | l;
      int be = dot >> 7, u2 = dot & 127;
      double a = 0;
      for (int s2 = 0; s2 < 50; s2++)
        a = fma((double)sRG[be][s2 * RSTR + u2], (double)sh_w[be][s2], a);
      sh_q2[be][u2] = (float)a;
    }
    __syncthreads();                               // B6

    // pointer query: qp = Wq_p @ q2 + bq_p (4 waves)
    if (w < 4) {
      int dot = (w << 6) | l;
      int be = dot >> 7, u2 = dot & 127;
      double a = dot128(PQP, u2, (const float4*)sh_q2[be]);
      sh_q[be][u2] = f_add((float)a, pbq[u2]);
    }
    __syncthreads();                               // B7

    // pointer logits + 10*tanh + mask; 8 lanes/row
    {
      double acc = 0.0;
      const int r = tid & 511;
      const int be = tid >> 9;
      const int s = r >> 3;
      const int f4o = (r & 7) * 4;
      if (r < 400) {
        const float4* rr = (const float4*)(&sRP[be][s * RSTR]) + f4o;
        const float4* qq = (const float4*)(sh_q[be]) + f4o;
        const float4* vvp = (const float4*)pV + f4o;
#pragma unroll
        for (int k4 = 0; k4 < 4; k4++) {
          float4 rv = rr[k4];
          float4 qv = qq[k4];
          float4 pvv = vvp[k4];
          acc = fma((double)pvv.x, (double)tanh_xla(f_add(qv.x, rv.x)), acc);
          acc = fma((double)pvv.y, (double)tanh_xla(f_add(qv.y, rv.y)), acc);
          acc = fma((double)pvv.z, (double)tanh_xla(f_add(qv.z, rv.z)), acc);
          acc = fma((double)pvv.w, (double)tanh_xla(f_add(qv.w, rv.w)), acc);
        }
      }
      double tot = acc + shfl_xor_d(acc, 1);
      tot = tot + shfl_xor_d(tot, 2);
      tot = tot + shfl_xor_d(tot, 4);
      if (r < 400 && (r & 7) == 0) {
        float lp = (float)tot;
        lp = f_mul(10.0f, tanh_xla(lp));
        sh_att[be][s] = ((sh_msk[be] >> s) & 1ull) ? NEG_INF : lp;
      }
      if (r >= 400 && r < 414) sh_att[be][r - 350] = NEG_INF;
    }
    __syncthreads();                               // B8

    // probs output + gumbel sampling: wave 0 -> be0, wave 8 -> be1
    if ((w & 7) == 0) {
      const int be = w >> 3;
      float v = sh_att[be][l];
      float m = v;
      for (int off = 32; off > 0; off >>= 1) m = fmaxf(m, __shfl_xor(m, off));
      float ex = (l < 50) ? expf(f_sub(v, m)) : 0.0f;
      float ss = 0.0f;
      for (int s2 = 0; s2 < 50; s2++) ss = f_add(ss, __shfl(ex, s2));
      if (l < 50) out[t * 25600 + (gb2 + be) * 50 + l] = __fdiv_rn(ex, ss);

      float val = NEG_INF;
      int ii = l;
      if (l < 50) {
        int j = (gb2 + be) * 50 + l;       // flat index into (B,S) gumbel draw
        uint32_t b0, b1;
        tf2x32(k1a, k1b, 0u, (uint32_t)j, b0, b1);
        uint32_t bits = b0 ^ b1;
        float fl = __uint_as_float((bits >> 9) | 0x3f800000u) - 1.0f;  // [0,1)
        float uu = f_add(fl, TINYF);
        uu = fmaxf(TINYF, uu);
        float gum = -logf(-logf(uu));
        val = f_add(v, gum);               // -inf stays -inf for masked
      }
      // argmax, first-index tiebreak (jnp.argmax semantics)
      for (int off = 32; off > 0; off >>= 1) {
        float ov = __shfl_down(val, off);
        int   oi = __shfl_down(ii, off);
        if (ov > val || (ov == val && oi < ii)) { val = ov; ii = oi; }
      }
      if (l == 0) {
        sh_idx[be] = ii;
        sh_msk[be] |= (1ull << ii);        // masks step t+1 onward
        out[1280000 + t * 512 + gb2 + be] = (float)ii;
      }
    }
    __syncthreads();                               // B9

    // next decoder input: embedded[b, idx]
    if (tid < 256) {
      int idx = sh_idx[cu_be];
      float x0 = bi[(gb2 + cu_be) * 100 + idx];
      float x1 = bi[(gb2 + cu_be) * 100 + 50 + idx];
      sh_x[cu_be][cu_u] = __fmaf_rn(x1, emb[128 + cu_u], f_mul(x0, emb[cu_u]));
    }
    __syncthreads();                               // B10
  }
}

extern "C" void kernel_launch(void* const* d_in, const int* in_sizes, int n_in,
                              void* d_out, int out_size, void* d_ws, size_t ws_size,
                              hipStream_t stream) {
  const float* bi     = (const float*)d_in[0];
  const float* emb    = (const float*)d_in[1];
  const float* eWih   = (const float*)d_in[2];
  const float* eWhh   = (const float*)d_in[3];
  const float* ebih   = (const float*)d_in[4];
  const float* ebhh   = (const float*)d_in[5];
  const float* dWih   = (const float*)d_in[6];
  const float* dWhh   = (const float*)d_in[7];
  const float* dbih   = (const float*)d_in[8];
  const float* dbhh   = (const float*)d_in[9];
  const float* gWq    = (const float*)d_in[10];
  const float* gbq    = (const float*)d_in[11];
  const float* gWref  = (const float*)d_in[12];
  const float* gbref  = (const float*)d_in[13];
  const float* gV     = (const float*)d_in[14];
  const float* pWq    = (const float*)d_in[15];
  const float* pbq    = (const float*)d_in[16];
  const float* pWref  = (const float*)d_in[17];
  const float* pbref  = (const float*)d_in[18];
  const float* pV     = (const float*)d_in[19];
  const float* dstart = (const float*)d_in[20];
  float* ws  = (float*)d_ws;
  float* out = (float*)d_out;

  hipLaunchKernelGGL(prep_kernel, dim3(1280), dim3(256), 0, stream,
                     eWih, eWhh, dWih, dWhh, gWq, gWref, pWq, pWref, ws);
  hipLaunchKernelGGL(pnet_kernel, dim3(256), dim3(1024), 0, stream,
                     bi, emb, ebih, ebhh, dbih, dbhh,
                     gbq, gbref, gV, pbq, pbref, pV, dstart, ws, out);
}